// Round 1
// baseline (168.434 us; speedup 1.0000x reference)
//
#include <hip/hip_runtime.h>
#include <math.h>

// FSCILGate: gate_scores = softmax(x @ q^T / T), aux = 0.01*mean(avg*load)*E^2
// x: [200704, 512] f32, q: [16, 512] f32, T: [1] f32
// out: [200704*16] gates + [1] aux_loss  (float32)
//
// Memory-bound (424 MB @ ~6.3 TB/s -> ~67 us floor). One wave per row:
// wave collectively holds ALL of q in registers (128 VGPR/lane), lane owns an
// 8-float d-slice (two float4s over two contiguous 1KB segments -> coalesced).
// Split-butterfly reduction (~64 ops vs 192 naive) leaves expert (l>>2)&15's
// logit on lane l; softmax/top-2 via xor-4/8/16/32 shuffles.

#define NROWS 200704  // 64*56*56
#define DDIM 512
#define NEXP 16

__global__ __launch_bounds__(256, 2) void gate_kernel(
    const float* __restrict__ x,
    const float* __restrict__ q,
    const float* __restrict__ temp,
    float* __restrict__ out,
    float* __restrict__ ws)
{
    const int lane = threadIdx.x & 63;
    const int gwave = (blockIdx.x << 2) + (threadIdx.x >> 6);  // 256 thr = 4 waves
    const int nwaves = gridDim.x << 2;

    const float invT = 1.0f / temp[0];

    // Preload q fragments: qa[e] = q[e][lane*4..+3], qb[e] = q[e][256+lane*4..+3]
    float4 qa[NEXP], qb[NEXP];
#pragma unroll
    for (int e = 0; e < NEXP; ++e) {
        qa[e] = *reinterpret_cast<const float4*>(q + e * DDIM + lane * 4);
        qb[e] = *reinterpret_cast<const float4*>(q + e * DDIM + 256 + lane * 4);
    }

    const bool up5 = (lane & 32) != 0;
    const bool up4 = (lane & 16) != 0;
    const bool up3 = (lane & 8) != 0;
    const bool up2 = (lane & 4) != 0;

    float sS = 0.0f;  // sum of gate scores for expert (lane>>2)&15
    float sC = 0.0f;  // top-2 membership count for that expert

    int row = gwave;
    float4 c0, c1;
    if (row < NROWS) {
        const float* xr = x + (size_t)row * DDIM;
        c0 = *reinterpret_cast<const float4*>(xr + lane * 4);
        c1 = *reinterpret_cast<const float4*>(xr + 256 + lane * 4);
    }

    while (row < NROWS) {
        const int nrow = row + nwaves;
        float4 n0, n1;
        if (nrow < NROWS) {  // prefetch next row while computing current
            const float* xr = x + (size_t)nrow * DDIM;
            n0 = *reinterpret_cast<const float4*>(xr + lane * 4);
            n1 = *reinterpret_cast<const float4*>(xr + 256 + lane * 4);
        }

        // Partial dots: acc[e] = x_slice . q[e]_slice  (8 FMAs each)
        float acc[NEXP];
#pragma unroll
        for (int e = 0; e < NEXP; ++e) {
            float a = c0.x * qa[e].x;
            a = fmaf(c0.y, qa[e].y, a);
            a = fmaf(c0.z, qa[e].z, a);
            a = fmaf(c0.w, qa[e].w, a);
            a = fmaf(c1.x, qb[e].x, a);
            a = fmaf(c1.y, qb[e].y, a);
            a = fmaf(c1.z, qb[e].z, a);
            a = fmaf(c1.w, qb[e].w, a);
            acc[e] = a;
        }

        // Split-butterfly reduce: 64x16 -> expert (l>>2)&15 on each lane.
#pragma unroll
        for (int k = 0; k < 8; ++k) {
            const float send = up5 ? acc[k] : acc[k + 8];
            const float keep = up5 ? acc[k + 8] : acc[k];
            acc[k] = keep + __shfl_xor(send, 32, 64);
        }
#pragma unroll
        for (int k = 0; k < 4; ++k) {
            const float send = up4 ? acc[k] : acc[k + 4];
            const float keep = up4 ? acc[k + 4] : acc[k];
            acc[k] = keep + __shfl_xor(send, 16, 64);
        }
#pragma unroll
        for (int k = 0; k < 2; ++k) {
            const float send = up3 ? acc[k] : acc[k + 2];
            const float keep = up3 ? acc[k + 2] : acc[k];
            acc[k] = keep + __shfl_xor(send, 8, 64);
        }
        {
            const float send = up2 ? acc[0] : acc[1];
            const float keep = up2 ? acc[1] : acc[0];
            acc[0] = keep + __shfl_xor(send, 4, 64);
        }
        acc[0] += __shfl_xor(acc[0], 2, 64);
        acc[0] += __shfl_xor(acc[0], 1, 64);

        const float logit = acc[0] * invT;

        // softmax across 16 experts (lane bits 2..5), 4 dup lanes per expert
        float m = logit;
        m = fmaxf(m, __shfl_xor(m, 4, 64));
        m = fmaxf(m, __shfl_xor(m, 8, 64));
        m = fmaxf(m, __shfl_xor(m, 16, 64));
        m = fmaxf(m, __shfl_xor(m, 32, 64));
        const float p = __expf(logit - m);
        float s = p;
        s += __shfl_xor(s, 4, 64);
        s += __shfl_xor(s, 8, 64);
        s += __shfl_xor(s, 16, 64);
        s += __shfl_xor(s, 32, 64);
        const float gate = p / s;

        // top-2: second max after masking the max instance
        float xm = (logit == m) ? -__builtin_inff() : logit;
        float m2 = xm;
        m2 = fmaxf(m2, __shfl_xor(m2, 4, 64));
        m2 = fmaxf(m2, __shfl_xor(m2, 8, 64));
        m2 = fmaxf(m2, __shfl_xor(m2, 16, 64));
        m2 = fmaxf(m2, __shfl_xor(m2, 32, 64));
        const bool topk = (logit >= m2);

        if ((lane & 3) == 0) {
            out[(size_t)row * NEXP + (lane >> 2)] = gate;
        }
        sS += gate;
        sC += topk ? 1.0f : 0.0f;

        c0 = n0;
        c1 = n1;
        row = nrow;
    }

    // Block-level reduction of stats, then global atomics (32 per block).
    __shared__ float sred[32];
    if (threadIdx.x < 32) sred[threadIdx.x] = 0.0f;
    __syncthreads();
    if ((lane & 3) == 0) {
        const int e = lane >> 2;
        atomicAdd(&sred[e], sS);
        atomicAdd(&sred[16 + e], sC);
    }
    __syncthreads();
    if (threadIdx.x < 32) atomicAdd(&ws[threadIdx.x], sred[threadIdx.x]);
}

// aux = 0.01 * mean_e(avg_e * load_e) * 256, avg_e = S_e/N, load_e = C_e/(2N)
//     = 0.08 * sum_e(S_e * C_e) / N^2
__global__ void aux_kernel(const float* __restrict__ ws, float* __restrict__ out) {
    if (threadIdx.x == 0 && blockIdx.x == 0) {
        float a = 0.0f;
#pragma unroll
        for (int e = 0; e < NEXP; ++e) a += ws[e] * ws[16 + e];
        const float n = (float)NROWS;
        out[(size_t)NROWS * NEXP] = 0.08f * a / (n * n);
    }
}

extern "C" void kernel_launch(void* const* d_in, const int* in_sizes, int n_in,
                              void* d_out, int out_size, void* d_ws, size_t ws_size,
                              hipStream_t stream) {
    const float* x = (const float*)d_in[0];
    const float* q = (const float*)d_in[1];
    const float* t = (const float*)d_in[2];
    float* out = (float*)d_out;
    float* ws = (float*)d_ws;

    hipMemsetAsync(ws, 0, 32 * sizeof(float), stream);
    // 1024 blocks * 4 waves = 4096 waves; 200704/4096 = 49 rows per wave exactly.
    gate_kernel<<<1024, 256, 0, stream>>>(x, q, t, out, ws);
    aux_kernel<<<1, 64, 0, stream>>>(ws, out);
}

// Round 2
// 117.276 us; speedup vs baseline: 1.4362x; 1.4362x over previous
//
#include <hip/hip_runtime.h>
#include <hip/hip_bf16.h>
#include <math.h>

// FSCILGate: gates = softmax(x @ q^T / T) [200704 x 16], plus scalar aux loss.
// Memory-bound: 411 MB x-read + 12.8 MB gate-write @ ~6.3 TB/s -> ~67 us floor.
//
// Structure: one wave computes a 16-row x 16-expert logit tile via 16x
// mfma_f32_16x16x32_bf16 (fp32 accumulate). A-fragments are loaded DIRECTLY
// from global in fragment layout (row=lane&15, k=(lane>>4)*8 + 32*step) --
// no LDS staging; every byte of each row's 128B step-segment is consumed.
// B-fragments (q, bf16) built once in the prologue (64 VGPRs).
// Epilogue: softmax + top-2 across the expert dim = lanes xor 1/2/4/8;
// 4 independent chains (one per C-reg) interleave to hide DS latency.
// C/D layout (HW-verified): col=lane&15 (expert), row=(lane>>4)*4+reg.
//
// 12544 tiles = 1792 waves x 7 (448 blocks x 4 waves; all resident @ 2
// blocks/CU) -- perfectly balanced single round.

#define NROWS 200704  // 64*56*56
#define DDIM 512
#define NEXP 16
#define KSTEPS 16     // 512 / 32
#define NTILES (NROWS / 16)      // 12544
#define NBLOCKS 448
#define NWAVES (NBLOCKS * 4)     // 1792 ; 12544 / 1792 = 7 tiles/wave exactly

typedef __attribute__((ext_vector_type(8))) short short8;
typedef __attribute__((ext_vector_type(4))) float f32x4;

static __device__ inline short f2bf(float f) {
    __bf16 h = (__bf16)f;  // RTNE convert; compiler emits cvt_pk pairs (m240)
    return __builtin_bit_cast(short, h);
}

static __device__ inline short8 pack8(float4 a, float4 b) {
    short8 r;
    r[0] = f2bf(a.x); r[1] = f2bf(a.y); r[2] = f2bf(a.z); r[3] = f2bf(a.w);
    r[4] = f2bf(b.x); r[5] = f2bf(b.y); r[6] = f2bf(b.z); r[7] = f2bf(b.w);
    return r;
}

__global__ __launch_bounds__(256, 2) void gate_kernel(
    const float* __restrict__ x,
    const float* __restrict__ q,
    const float* __restrict__ temp,
    float* __restrict__ out,
    float* __restrict__ ws)
{
    const int lane = threadIdx.x & 63;
    const int wid  = threadIdx.x >> 6;
    const int gwave = blockIdx.x * 4 + wid;
    const int e = lane & 15;   // expert (B col / C col); also A row within tile
    const int g = lane >> 4;   // k-group: fragment holds k = g*8 .. g*8+7

    const float invT = 1.0f / temp[0];

    // B fragments: bq[s] = q[e][32*s + g*8 .. +8] as bf16. 64 VGPRs, built once.
    short8 bq[KSTEPS];
    {
        const float* qp = q + e * DDIM + g * 8;
#pragma unroll
        for (int s = 0; s < KSTEPS; ++s) {
            float4 a = *reinterpret_cast<const float4*>(qp + s * 32);
            float4 b = *reinterpret_cast<const float4*>(qp + s * 32 + 4);
            bq[s] = pack8(a, b);
        }
    }

    float sS = 0.0f;  // gate-score sum for expert e (this lane's share)
    float sC = 0.0f;  // top-2 membership count for expert e

    for (int t = gwave; t < NTILES; t += NWAVES) {
        // A-fragment loads: row = e (lane&15), k-slice g*8, stepping 32/step.
        const float* xr = x + (size_t)t * 16 * DDIM + (size_t)e * DDIM + g * 8;
        float4 a0[KSTEPS], a1[KSTEPS];
#pragma unroll
        for (int s = 0; s < KSTEPS; ++s) {
            a0[s] = *reinterpret_cast<const float4*>(xr + s * 32);
            a1[s] = *reinterpret_cast<const float4*>(xr + s * 32 + 4);
        }

        f32x4 acc = {0.0f, 0.0f, 0.0f, 0.0f};
#pragma unroll
        for (int s = 0; s < KSTEPS; ++s) {
            acc = __builtin_amdgcn_mfma_f32_16x16x32_bf16(
                pack8(a0[s], a1[s]), bq[s], acc, 0, 0, 0);
        }

        // Epilogue: per C-reg r, row = t*16 + g*4 + r, expert = e.
        // Softmax / top-2 reduce across expert dim = lanes xor 1/2/4/8.
#pragma unroll
        for (int r = 0; r < 4; ++r) {
            const float logit = acc[r] * invT;
            float m = logit;
            m = fmaxf(m, __shfl_xor(m, 1, 64));
            m = fmaxf(m, __shfl_xor(m, 2, 64));
            m = fmaxf(m, __shfl_xor(m, 4, 64));
            m = fmaxf(m, __shfl_xor(m, 8, 64));
            const float p = __expf(logit - m);
            float s = p;
            s += __shfl_xor(s, 1, 64);
            s += __shfl_xor(s, 2, 64);
            s += __shfl_xor(s, 4, 64);
            s += __shfl_xor(s, 8, 64);
            const float gate = p / s;

            float m2 = (logit == m) ? -3.4e38f : logit;  // mask top-1
            m2 = fmaxf(m2, __shfl_xor(m2, 1, 64));
            m2 = fmaxf(m2, __shfl_xor(m2, 2, 64));
            m2 = fmaxf(m2, __shfl_xor(m2, 4, 64));
            m2 = fmaxf(m2, __shfl_xor(m2, 8, 64));
            const bool topk = (logit >= m2);

            const int row = t * 16 + g * 4 + r;
            out[(size_t)row * NEXP + e] = gate;
            sS += gate;
            sC += topk ? 1.0f : 0.0f;
        }
    }

    // Stats: fold the 4 k-groups (same expert e at lanes e, e+16, e+32, e+48).
    sS += __shfl_xor(sS, 16, 64); sS += __shfl_xor(sS, 32, 64);
    sC += __shfl_xor(sC, 16, 64); sC += __shfl_xor(sC, 32, 64);

    __shared__ float sred[32];
    if (threadIdx.x < 32) sred[threadIdx.x] = 0.0f;
    __syncthreads();
    if (lane < 16) {
        atomicAdd(&sred[e], sS);
        atomicAdd(&sred[16 + e], sC);
    }
    __syncthreads();
    if (threadIdx.x < 32) atomicAdd(&ws[threadIdx.x], sred[threadIdx.x]);
}

// aux = 0.01 * mean_e(avg_e * load_e) * 256 = 0.08 * sum_e(S_e * C_e) / N^2
__global__ void aux_kernel(const float* __restrict__ ws, float* __restrict__ out) {
    if (threadIdx.x == 0 && blockIdx.x == 0) {
        float a = 0.0f;
#pragma unroll
        for (int e = 0; e < NEXP; ++e) a += ws[e] * ws[16 + e];
        const float n = (float)NROWS;
        out[(size_t)NROWS * NEXP] = 0.08f * a / (n * n);
    }
}

extern "C" void kernel_launch(void* const* d_in, const int* in_sizes, int n_in,
                              void* d_out, int out_size, void* d_ws, size_t ws_size,
                              hipStream_t stream) {
    const float* x = (const float*)d_in[0];
    const float* q = (const float*)d_in[1];
    const float* t = (const float*)d_in[2];
    float* out = (float*)d_out;
    float* ws = (float*)d_ws;

    hipMemsetAsync(ws, 0, 32 * sizeof(float), stream);
    gate_kernel<<<NBLOCKS, 256, 0, stream>>>(x, q, t, out, ws);
    aux_kernel<<<1, 64, 0, stream>>>(ws, out);
}